// Round 14
// baseline (69.331 us; speedup 1.0000x reference)
//
#include <hip/hip_runtime.h>

#define N_NODES 50000
#define N_EDGES 800000

#define NBUCKETS 782      // ceil(50000/64): bucket = dst >> 6 (64 nodes each)
#define BIN_EDGES 16384   // edges per bin block: ~21 edges/bucket-run -> ~1.3x
                          // line utilization on bucketbuf (r13 lesson: small
                          // runs re-create the fill_kernel write amplification)
#define BIN_NB 49         // ceil(800000/16384)
#define BUCKET_CAP 1280   // slots per bucket (mean ~1023, sd ~32 -> +8 sigma)

#define GEMM_NB ((N_NODES + 63) / 64)          // 782 gemm tiles (64 rows each)
#define FUSED_NB (BIN_NB + GEMM_NB)            // 831; bid<49 -> bin role

typedef __attribute__((ext_vector_type(4))) _Float16 half4;
typedef __attribute__((ext_vector_type(8))) _Float16 half8;
typedef __attribute__((ext_vector_type(4))) float f32x4;

// -------- Prep: Wt[c][k] = fp16(W[k][c]); block 0 zeroes bcur -------------
// 32 KB fp16 transposed W; L2-hot source for the GEMM role's LDS stage.
__global__ __launch_bounds__(256) void prep_wt_kernel(
    const float* __restrict__ W, _Float16* __restrict__ Wt,
    int* __restrict__ bcur)
{
    const int tid = threadIdx.x;
    if (blockIdx.x == 0) {
        for (int i = tid; i < NBUCKETS; i += 256) bcur[i] = 0;
    }
    const int e = blockIdx.x * 256 + tid;           // 4096 threads
    const int c = e & 127;
    const int k4 = (e >> 7) << 2;
    half4 v;
    v.x = (_Float16)W[(k4 + 0) * 128 + c];
    v.y = (_Float16)W[(k4 + 1) * 128 + c];
    v.z = (_Float16)W[(k4 + 2) * 128 + c];
    v.w = (_Float16)W[(k4 + 3) * 128 + c];
    *(half4*)(Wt + (size_t)c * 128 + k4) = v;
}

// -------- Fused Kernel A: MFMA gemm tiles + edge binning ------------------
// Blocks bid<49 bin 16384 edges each into per-bucket streams of PACKED
// ints (src | (dst&63)<<16; src<65536) — dispatched first so their longer
// runtime hides under the 782 GEMM blocks. Other blocks: one 64-row GEMM
// tile (4 waves x 16 rows), mfma_f32_16x16x32_f16; Wt staged once into LDS
// (pad 136 halves -> conflict-free ds_read_b128), A-frags straight from h.
// hist (3.1 KB) is UNIONED with WtS (34.8 KB): the two roles never share.
// Fragment layout (guide-verified 16x16x32): A/B lane l&15 = row/col,
// k = (l>>4)*8 + j; C/D col = l&15, row = (l>>4)*4 + reg.
// SESSION RULE (rounds 2 & 4): no min-waves clause — it collapses VGPRs and
// spills the accumulators (WRITE_SIZE tripwire 12.5 MB -> 183-564 MB).
__global__ __launch_bounds__(256) void fused_gemm_bin_kernel(
    const float* __restrict__ h, const float* __restrict__ norm,
    const _Float16* __restrict__ Wt, _Float16* __restrict__ t,
    const int* __restrict__ src, const int* __restrict__ dst,
    int* __restrict__ bcur, int* __restrict__ bucketbuf)
{
    __shared__ __align__(16) char smem[128 * 136 * 2];  // 34.8 KB union
    _Float16* WtS = (_Float16*)smem;                    // gemm role
    int* hist = (int*)smem;                             // bin role (3.1 KB)
    const int tid = threadIdx.x;
    const int bid = blockIdx.x;

    if (bid < BIN_NB) {
        // ---- bin role: 16384 edges -> 782 bucket streams -------------------
        const int bs = bid * BIN_EDGES;
        for (int i = tid; i < NBUCKETS; i += 256) hist[i] = 0;
        __syncthreads();
#pragma unroll
        for (int j = 0; j < 16; ++j) {
            int e4 = bs + (j * 256 + tid) * 4;
            if (e4 < N_EDGES) {               // 16384 & 13568 both %4==0
                int4 d4 = *(const int4*)(dst + e4);
                atomicAdd(&hist[d4.x >> 6], 1);
                atomicAdd(&hist[d4.y >> 6], 1);
                atomicAdd(&hist[d4.z >> 6], 1);
                atomicAdd(&hist[d4.w >> 6], 1);
            }
        }
        __syncthreads();
        for (int i = tid; i < NBUCKETS; i += 256) {
            int hc = hist[i];
            hist[i] = hc ? atomicAdd(&bcur[i], hc) : 0;
        }
        __syncthreads();
#pragma unroll
        for (int j = 0; j < 16; ++j) {
            int e4 = bs + (j * 256 + tid) * 4;
            if (e4 < N_EDGES) {
                int4 d4 = *(const int4*)(dst + e4);
                int4 s4 = *(const int4*)(src + e4);
                int b0, p;
                b0 = d4.x >> 6; p = atomicAdd(&hist[b0], 1);
                bucketbuf[(size_t)b0 * BUCKET_CAP + p] = s4.x | ((d4.x & 63) << 16);
                b0 = d4.y >> 6; p = atomicAdd(&hist[b0], 1);
                bucketbuf[(size_t)b0 * BUCKET_CAP + p] = s4.y | ((d4.y & 63) << 16);
                b0 = d4.z >> 6; p = atomicAdd(&hist[b0], 1);
                bucketbuf[(size_t)b0 * BUCKET_CAP + p] = s4.z | ((d4.z & 63) << 16);
                b0 = d4.w >> 6; p = atomicAdd(&hist[b0], 1);
                bucketbuf[(size_t)b0 * BUCKET_CAP + p] = s4.w | ((d4.w & 63) << 16);
            }
        }
        return;
    }

    // ---- gemm role: one 64-row tile, 4 waves x 16 rows ---------------------
    const int gemm_id = bid - BIN_NB;
    if (gemm_id >= GEMM_NB) return;
    const int rbase = gemm_id * 64;

    // stage Wt into LDS once (8 x half8 per thread, coalesced), one barrier
#pragma unroll
    for (int i = 0; i < 8; ++i) {
        int f = i * 256 + tid;            // 0..2047
        int c = f >> 4;                   // 0..127
        int k8 = (f & 15) << 3;           // 0..120
        *(half8*)(WtS + c * 136 + k8) = *(const half8*)(Wt + (size_t)c * 128 + k8);
    }
    __syncthreads();

    const int wid = tid >> 6, lane = tid & 63;
    const int lrow = lane & 15;            // A row / B col within 16-tile
    const int khi = (lane >> 4) << 3;      // k octet (in halves)
    const int r0 = wid * 16;
    const int gr = rbase + r0 + lrow;      // this lane's A row

    // A fragments straight from h (fp32 -> fp16), 8 float4 loads in flight
    half8 a[4];
#pragma unroll
    for (int ks = 0; ks < 4; ++ks) {
        float4 f0 = make_float4(0.f, 0.f, 0.f, 0.f);
        float4 f1 = f0;
        if (gr < N_NODES) {
            const float* hp = h + (size_t)gr * 128 + ks * 32 + khi;
            f0 = *(const float4*)hp;
            f1 = *(const float4*)(hp + 4);
        }
        half8 av;
        av[0] = (_Float16)f0.x; av[1] = (_Float16)f0.y;
        av[2] = (_Float16)f0.z; av[3] = (_Float16)f0.w;
        av[4] = (_Float16)f1.x; av[5] = (_Float16)f1.y;
        av[6] = (_Float16)f1.z; av[7] = (_Float16)f1.w;
        a[ks] = av;
    }

    // per-lane output rows (fixed across col-tiles) + their norms (L2-hot)
    const int rq = rbase + r0 + ((lane >> 4) << 2);
    float nv[4];
#pragma unroll
    for (int reg = 0; reg < 4; ++reg)
        nv[reg] = (rq + reg < N_NODES) ? norm[rq + reg] : 0.f;

#pragma unroll
    for (int ct = 0; ct < 8; ++ct) {
        const int c0 = ct * 16;
        f32x4 acc = {0.f, 0.f, 0.f, 0.f};
#pragma unroll
        for (int ks = 0; ks < 4; ++ks) {
            half8 bf = *(const half8*)(WtS + (c0 + lrow) * 136 + ks * 32 + khi);
            acc = __builtin_amdgcn_mfma_f32_16x16x32_f16(a[ks], bf, acc, 0, 0, 0);
        }
#pragma unroll
        for (int reg = 0; reg < 4; ++reg) {
            if (rq + reg < N_NODES)
                t[(size_t)(rq + reg) * 128 + c0 + lrow] = (_Float16)(acc[reg] * nv[reg]);
        }
    }
}

// -------- Fused scatter+aggregate: sort bucket in LDS, gather, finalize ---
// One block per 64-node bucket (782 blocks, round-12 config — the 32-node
// variant regressed via bin-side write amplification). Phase 1: LDS
// histogram + 1-wave shfl scan. Phase 2: place sorted srcs into slist
// (5 KB LDS) — the sorted edge list never goes to global. Phase 3: 16
// groups of 16 lanes aggregate 4 nodes each (x4-unrolled gathers for MLP);
// deg-0 nodes produce acc=0 -> out = b.
__global__ __launch_bounds__(256) void scatter_aggregate_kernel(
    const int* __restrict__ bucketbuf, const int* __restrict__ bcur,
    const _Float16* __restrict__ t, const float* __restrict__ norm,
    const float* __restrict__ bias, float* __restrict__ out)
{
    const int tid = threadIdx.x;
    const int b = blockIdx.x;
    __shared__ int cnt[64];     // per-node counts (kept)
    __shared__ int endp[64];    // inclusive scan (segment ends)
    __shared__ int lcur[64];    // running cursors (start -> end)
    __shared__ int slist[BUCKET_CAP];

    if (tid < 64) cnt[tid] = 0;
    __syncthreads();

    const int n = bcur[b];
    const int* buf = bucketbuf + (size_t)b * BUCKET_CAP;
    for (int i = tid; i < n; i += 256)
        atomicAdd(&cnt[(buf[i] >> 16) & 63], 1);
    __syncthreads();

    if (tid < 64) {             // single-wave inclusive scan over 64 counts
        int c = cnt[tid];
        int inc = c;
#pragma unroll
        for (int d = 1; d < 64; d <<= 1) {
            int u = __shfl_up(inc, d);
            if (tid >= d) inc += u;
        }
        endp[tid] = inc;
        lcur[tid] = inc - c;    // exclusive start
    }
    __syncthreads();

    for (int i = tid; i < n; i += 256) {
        int p = buf[i];
        int pos = atomicAdd(&lcur[(p >> 16) & 63], 1);
        slist[pos] = p & 0xFFFF;
    }
    __syncthreads();

    // ---- aggregate phase: group q handles nodes q, q+16, q+32, q+48 -------
    const int q = tid >> 4, l = tid & 15, c = l << 3;
    const float4 b0 = *(const float4*)(bias + c);
    const float4 b1 = *(const float4*)(bias + c + 4);

    for (int r = 0; r < 4; ++r) {
        const int nl = q + (r << 4);
        const int g = b * 64 + nl;
        if (g >= N_NODES) continue;
        const int i1 = endp[nl];
        const int i0 = i1 - cnt[nl];

        float acc0[8], acc1[8], acc2[8], acc3[8];
#pragma unroll
        for (int j = 0; j < 8; ++j) {
            acc0[j] = 0.f; acc1[j] = 0.f; acc2[j] = 0.f; acc3[j] = 0.f;
        }

        int i = i0;
        for (; i + 4 <= i1; i += 4) {
            int s0 = slist[i], s1 = slist[i + 1];
            int s2 = slist[i + 2], s3 = slist[i + 3];
            half8 v0 = *(const half8*)(t + (size_t)s0 * 128 + c);
            half8 v1 = *(const half8*)(t + (size_t)s1 * 128 + c);
            half8 v2 = *(const half8*)(t + (size_t)s2 * 128 + c);
            half8 v3 = *(const half8*)(t + (size_t)s3 * 128 + c);
#pragma unroll
            for (int j = 0; j < 8; ++j) {
                acc0[j] += (float)v0[j]; acc1[j] += (float)v1[j];
                acc2[j] += (float)v2[j]; acc3[j] += (float)v3[j];
            }
        }
        for (; i < i1; ++i) {
            int s0 = slist[i];
            half8 v0 = *(const half8*)(t + (size_t)s0 * 128 + c);
#pragma unroll
            for (int j = 0; j < 8; ++j) acc0[j] += (float)v0[j];
        }

        const float nv = norm[g];
        float4 o0 = make_float4((acc0[0] + acc1[0] + acc2[0] + acc3[0]) * nv + b0.x,
                                (acc0[1] + acc1[1] + acc2[1] + acc3[1]) * nv + b0.y,
                                (acc0[2] + acc1[2] + acc2[2] + acc3[2]) * nv + b0.z,
                                (acc0[3] + acc1[3] + acc2[3] + acc3[3]) * nv + b0.w);
        float4 o1 = make_float4((acc0[4] + acc1[4] + acc2[4] + acc3[4]) * nv + b1.x,
                                (acc0[5] + acc1[5] + acc2[5] + acc3[5]) * nv + b1.y,
                                (acc0[6] + acc1[6] + acc2[6] + acc3[6]) * nv + b1.z,
                                (acc0[7] + acc1[7] + acc2[7] + acc3[7]) * nv + b1.w);
        *(float4*)(out + (size_t)g * 128 + c) = o0;
        *(float4*)(out + (size_t)g * 128 + c + 4) = o1;
    }
}

static inline size_t align256(size_t x) { return (x + 255) & ~(size_t)255; }

extern "C" void kernel_launch(void* const* d_in, const int* in_sizes, int n_in,
                              void* d_out, int out_size, void* d_ws, size_t ws_size,
                              hipStream_t stream)
{
    const float* h    = (const float*)d_in[0];
    const float* norm = (const float*)d_in[1];
    const float* W    = (const float*)d_in[2];
    const float* b    = (const float*)d_in[3];
    const int*   src  = (const int*)d_in[4];
    const int*   dst  = (const int*)d_in[5];
    float* out = (float*)d_out;

    // workspace layout
    char* ws = (char*)d_ws;
    size_t o = 0;
    _Float16* t = (_Float16*)(ws + o);  o = align256(o + (size_t)N_NODES * 128 * 2);
    _Float16* Wt = (_Float16*)(ws + o); o = align256(o + (size_t)128 * 128 * 2);
    int* bcur = (int*)(ws + o);         o = align256(o + (size_t)NBUCKETS * 4);
    int* bucketbuf = (int*)(ws + o);    o = align256(o + (size_t)NBUCKETS * BUCKET_CAP * 4);

    prep_wt_kernel<<<16, 256, 0, stream>>>(W, Wt, bcur);
    fused_gemm_bin_kernel<<<FUSED_NB, 256, 0, stream>>>(h, norm, Wt, t,
                                                        src, dst, bcur, bucketbuf);
    scatter_aggregate_kernel<<<NBUCKETS, 256, 0, stream>>>(bucketbuf, bcur,
                                                           t, norm, b, out);
}

// Round 15
// 63.286 us; speedup vs baseline: 1.0955x; 1.0955x over previous
//
#include <hip/hip_runtime.h>

#define N_NODES 50000
#define N_EDGES 800000

#define NBUCKETS 782      // ceil(50000/64): bucket = dst >> 6 (64 nodes each)
#define BIN_EDGES 4096    // ROUND-14 LESSON: keep bin blocks small & many
                          // (49 x 16384 made bin blocks the critical path:
                          // fused dur 43-50us at 3% VALUBusy). 196 x 4096
                          // interleaved every 5th block is the proven config.
#define BIN_NB 196        // ceil(800000/4096)
#define BUCKET_CAP 1280   // slots per bucket (mean ~1023, sd ~32 -> +8 sigma)
#define HALF_CAP 768      // slots per half-bucket (mean 512, sd ~23 -> +11 sigma)

#define GEMM_NB ((N_NODES + 63) / 64)          // 782 gemm tiles (64 rows each)
#define FUSED_NB 980                           // 196*5; bid%5==4 -> bin role

typedef __attribute__((ext_vector_type(4))) _Float16 half4;
typedef __attribute__((ext_vector_type(8))) _Float16 half8;
typedef __attribute__((ext_vector_type(4))) float f32x4;

// -------- Prep: Wt[c][k] = fp16(W[k][c]); block 0 zeroes bcur -------------
// 32 KB fp16 transposed W; L2-hot source for the GEMM role's LDS stage.
__global__ __launch_bounds__(256) void prep_wt_kernel(
    const float* __restrict__ W, _Float16* __restrict__ Wt,
    int* __restrict__ bcur)
{
    const int tid = threadIdx.x;
    if (blockIdx.x == 0) {
        for (int i = tid; i < NBUCKETS; i += 256) bcur[i] = 0;
    }
    const int e = blockIdx.x * 256 + tid;           // 4096 threads
    const int c = e & 127;
    const int k4 = (e >> 7) << 2;
    half4 v;
    v.x = (_Float16)W[(k4 + 0) * 128 + c];
    v.y = (_Float16)W[(k4 + 1) * 128 + c];
    v.z = (_Float16)W[(k4 + 2) * 128 + c];
    v.w = (_Float16)W[(k4 + 3) * 128 + c];
    *(half4*)(Wt + (size_t)c * 128 + k4) = v;
}

// -------- Fused Kernel A: MFMA gemm tiles + edge binning ------------------
// ROUND-12 CONFIG (measured 60.1us total): blocks with bid%5==4 bin 4096
// edges into per-bucket streams of PACKED ints (src | (dst&63)<<16;
// src<65536). Other blocks: one 64-row GEMM tile (4 waves x 16 rows),
// mfma_f32_16x16x32_f16; Wt staged once into LDS (pad 136 halves ->
// conflict-free ds_read_b128), A-frags straight from h. hist (3.1 KB)
// unioned with WtS (34.8 KB) — the two roles never share.
// Fragment layout (guide-verified 16x16x32): A/B lane l&15 = row/col,
// k = (l>>4)*8 + j; C/D col = l&15, row = (l>>4)*4 + reg.
// SESSION RULE (rounds 2 & 4): no min-waves clause — it collapses VGPRs and
// spills the accumulators (WRITE_SIZE tripwire 12.5 MB -> 183-564 MB).
__global__ __launch_bounds__(256) void fused_gemm_bin_kernel(
    const float* __restrict__ h, const float* __restrict__ norm,
    const _Float16* __restrict__ Wt, _Float16* __restrict__ t,
    const int* __restrict__ src, const int* __restrict__ dst,
    int* __restrict__ bcur, int* __restrict__ bucketbuf)
{
    __shared__ __align__(16) char smem[128 * 136 * 2];  // 34.8 KB union
    _Float16* WtS = (_Float16*)smem;                    // gemm role
    int* hist = (int*)smem;                             // bin role (3.1 KB)
    const int tid = threadIdx.x;
    const int bid = blockIdx.x;

    if (bid % 5 == 4) {
        // ---- bin role: 4096 edges -> 782 bucket streams --------------------
        const int bs = (bid / 5) * BIN_EDGES;
        for (int i = tid; i < NBUCKETS; i += 256) hist[i] = 0;
        __syncthreads();
#pragma unroll
        for (int j = 0; j < 4; ++j) {
            int e4 = bs + (j * 256 + tid) * 4;
            if (e4 < N_EDGES) {               // 4096 & 1280 both %4==0
                int4 d4 = *(const int4*)(dst + e4);
                atomicAdd(&hist[d4.x >> 6], 1);
                atomicAdd(&hist[d4.y >> 6], 1);
                atomicAdd(&hist[d4.z >> 6], 1);
                atomicAdd(&hist[d4.w >> 6], 1);
            }
        }
        __syncthreads();
        for (int i = tid; i < NBUCKETS; i += 256) {
            int hc = hist[i];
            hist[i] = hc ? atomicAdd(&bcur[i], hc) : 0;
        }
        __syncthreads();
#pragma unroll
        for (int j = 0; j < 4; ++j) {
            int e4 = bs + (j * 256 + tid) * 4;
            if (e4 < N_EDGES) {
                int4 d4 = *(const int4*)(dst + e4);
                int4 s4 = *(const int4*)(src + e4);
                int b0, p;
                b0 = d4.x >> 6; p = atomicAdd(&hist[b0], 1);
                bucketbuf[(size_t)b0 * BUCKET_CAP + p] = s4.x | ((d4.x & 63) << 16);
                b0 = d4.y >> 6; p = atomicAdd(&hist[b0], 1);
                bucketbuf[(size_t)b0 * BUCKET_CAP + p] = s4.y | ((d4.y & 63) << 16);
                b0 = d4.z >> 6; p = atomicAdd(&hist[b0], 1);
                bucketbuf[(size_t)b0 * BUCKET_CAP + p] = s4.z | ((d4.z & 63) << 16);
                b0 = d4.w >> 6; p = atomicAdd(&hist[b0], 1);
                bucketbuf[(size_t)b0 * BUCKET_CAP + p] = s4.w | ((d4.w & 63) << 16);
            }
        }
        return;
    }

    // ---- gemm role: one 64-row tile, 4 waves x 16 rows ---------------------
    const int gemm_id = bid - bid / 5 - 1;
    if (gemm_id >= GEMM_NB || gemm_id < 0) return;
    const int rbase = gemm_id * 64;

    // stage Wt into LDS once (8 x half8 per thread, coalesced), one barrier
#pragma unroll
    for (int i = 0; i < 8; ++i) {
        int f = i * 256 + tid;            // 0..2047
        int c = f >> 4;                   // 0..127
        int k8 = (f & 15) << 3;           // 0..120
        *(half8*)(WtS + c * 136 + k8) = *(const half8*)(Wt + (size_t)c * 128 + k8);
    }
    __syncthreads();

    const int wid = tid >> 6, lane = tid & 63;
    const int lrow = lane & 15;            // A row / B col within 16-tile
    const int khi = (lane >> 4) << 3;      // k octet (in halves)
    const int r0 = wid * 16;
    const int gr = rbase + r0 + lrow;      // this lane's A row

    // A fragments straight from h (fp32 -> fp16), 8 float4 loads in flight
    half8 a[4];
#pragma unroll
    for (int ks = 0; ks < 4; ++ks) {
        float4 f0 = make_float4(0.f, 0.f, 0.f, 0.f);
        float4 f1 = f0;
        if (gr < N_NODES) {
            const float* hp = h + (size_t)gr * 128 + ks * 32 + khi;
            f0 = *(const float4*)hp;
            f1 = *(const float4*)(hp + 4);
        }
        half8 av;
        av[0] = (_Float16)f0.x; av[1] = (_Float16)f0.y;
        av[2] = (_Float16)f0.z; av[3] = (_Float16)f0.w;
        av[4] = (_Float16)f1.x; av[5] = (_Float16)f1.y;
        av[6] = (_Float16)f1.z; av[7] = (_Float16)f1.w;
        a[ks] = av;
    }

    // per-lane output rows (fixed across col-tiles) + their norms (L2-hot)
    const int rq = rbase + r0 + ((lane >> 4) << 2);
    float nv[4];
#pragma unroll
    for (int reg = 0; reg < 4; ++reg)
        nv[reg] = (rq + reg < N_NODES) ? norm[rq + reg] : 0.f;

#pragma unroll
    for (int ct = 0; ct < 8; ++ct) {
        const int c0 = ct * 16;
        f32x4 acc = {0.f, 0.f, 0.f, 0.f};
#pragma unroll
        for (int ks = 0; ks < 4; ++ks) {
            half8 bf = *(const half8*)(WtS + (c0 + lrow) * 136 + ks * 32 + khi);
            acc = __builtin_amdgcn_mfma_f32_16x16x32_f16(a[ks], bf, acc, 0, 0, 0);
        }
#pragma unroll
        for (int reg = 0; reg < 4; ++reg) {
            if (rq + reg < N_NODES)
                t[(size_t)(rq + reg) * 128 + c0 + lrow] = (_Float16)(acc[reg] * nv[reg]);
        }
    }
}

// -------- Fused scatter+aggregate: 2 blocks per bucket --------------------
// ROUND-15 CHANGE: grid 782 -> 1564 (2 blocks per 64-node bucket, ~6
// blocks/CU = ~24 waves/CU). Each half-block streams the full bucket
// segment but keeps only its 32 nodes (bit 21 of the packed word), sorts
// ~512 edges into a 3 KB slist, then 16 groups x 16 lanes aggregate 2
// nodes each (x4-unrolled gathers). The gather phase is outstanding-
// request-limited (~3 TB/s at 12 waves/CU in round 1); doubling resident
// waves raises in-flight requests without touching the bin role (the
// round-13/14 regressions were both bin-side).
__global__ __launch_bounds__(256) void scatter_aggregate_kernel(
    const int* __restrict__ bucketbuf, const int* __restrict__ bcur,
    const _Float16* __restrict__ t, const float* __restrict__ norm,
    const float* __restrict__ bias, float* __restrict__ out)
{
    const int tid = threadIdx.x;
    const int b = blockIdx.x >> 1;       // bucket
    const int half = blockIdx.x & 1;     // which 32 nodes of the bucket
    __shared__ int cnt[32];     // per-node counts (kept)
    __shared__ int endp[32];    // inclusive scan (segment ends)
    __shared__ int lcur[32];    // running cursors (start -> end)
    __shared__ int slist[HALF_CAP];

    if (tid < 32) cnt[tid] = 0;
    __syncthreads();

    const int n = bcur[b];
    const int* buf = bucketbuf + (size_t)b * BUCKET_CAP;
    for (int i = tid; i < n; i += 256) {
        int p = buf[i];
        if (((p >> 21) & 1) == half)
            atomicAdd(&cnt[(p >> 16) & 31], 1);
    }
    __syncthreads();

    if (tid < 32) {             // single-wave inclusive scan over 32 counts
        int c = cnt[tid];
        int inc = c;
#pragma unroll
        for (int d = 1; d < 32; d <<= 1) {
            int u = __shfl_up(inc, d);
            if (tid >= d) inc += u;
        }
        endp[tid] = inc;
        lcur[tid] = inc - c;    // exclusive start
    }
    __syncthreads();

    for (int i = tid; i < n; i += 256) {
        int p = buf[i];
        if (((p >> 21) & 1) == half) {
            int pos = atomicAdd(&lcur[(p >> 16) & 31], 1);
            slist[pos] = p & 0xFFFF;
        }
    }
    __syncthreads();

    // ---- aggregate phase: group q handles nodes q and q+16 ----------------
    const int q = tid >> 4, l = tid & 15, c = l << 3;
    const float4 b0 = *(const float4*)(bias + c);
    const float4 b1 = *(const float4*)(bias + c + 4);

    for (int r = 0; r < 2; ++r) {
        const int nl = q + (r << 4);
        const int g = b * 64 + half * 32 + nl;
        if (g >= N_NODES) continue;
        const int i1 = endp[nl];
        const int i0 = i1 - cnt[nl];

        float acc0[8], acc1[8], acc2[8], acc3[8];
#pragma unroll
        for (int j = 0; j < 8; ++j) {
            acc0[j] = 0.f; acc1[j] = 0.f; acc2[j] = 0.f; acc3[j] = 0.f;
        }

        int i = i0;
        for (; i + 4 <= i1; i += 4) {
            int s0 = slist[i], s1 = slist[i + 1];
            int s2 = slist[i + 2], s3 = slist[i + 3];
            half8 v0 = *(const half8*)(t + (size_t)s0 * 128 + c);
            half8 v1 = *(const half8*)(t + (size_t)s1 * 128 + c);
            half8 v2 = *(const half8*)(t + (size_t)s2 * 128 + c);
            half8 v3 = *(const half8*)(t + (size_t)s3 * 128 + c);
#pragma unroll
            for (int j = 0; j < 8; ++j) {
                acc0[j] += (float)v0[j]; acc1[j] += (float)v1[j];
                acc2[j] += (float)v2[j]; acc3[j] += (float)v3[j];
            }
        }
        for (; i < i1; ++i) {
            int s0 = slist[i];
            half8 v0 = *(const half8*)(t + (size_t)s0 * 128 + c);
#pragma unroll
            for (int j = 0; j < 8; ++j) acc0[j] += (float)v0[j];
        }

        const float nv = norm[g];
        float4 o0 = make_float4((acc0[0] + acc1[0] + acc2[0] + acc3[0]) * nv + b0.x,
                                (acc0[1] + acc1[1] + acc2[1] + acc3[1]) * nv + b0.y,
                                (acc0[2] + acc1[2] + acc2[2] + acc3[2]) * nv + b0.z,
                                (acc0[3] + acc1[3] + acc2[3] + acc3[3]) * nv + b0.w);
        float4 o1 = make_float4((acc0[4] + acc1[4] + acc2[4] + acc3[4]) * nv + b1.x,
                                (acc0[5] + acc1[5] + acc2[5] + acc3[5]) * nv + b1.y,
                                (acc0[6] + acc1[6] + acc2[6] + acc3[6]) * nv + b1.z,
                                (acc0[7] + acc1[7] + acc2[7] + acc3[7]) * nv + b1.w);
        *(float4*)(out + (size_t)g * 128 + c) = o0;
        *(float4*)(out + (size_t)g * 128 + c + 4) = o1;
    }
}

static inline size_t align256(size_t x) { return (x + 255) & ~(size_t)255; }

extern "C" void kernel_launch(void* const* d_in, const int* in_sizes, int n_in,
                              void* d_out, int out_size, void* d_ws, size_t ws_size,
                              hipStream_t stream)
{
    const float* h    = (const float*)d_in[0];
    const float* norm = (const float*)d_in[1];
    const float* W    = (const float*)d_in[2];
    const float* b    = (const float*)d_in[3];
    const int*   src  = (const int*)d_in[4];
    const int*   dst  = (const int*)d_in[5];
    float* out = (float*)d_out;

    // workspace layout
    char* ws = (char*)d_ws;
    size_t o = 0;
    _Float16* t = (_Float16*)(ws + o);  o = align256(o + (size_t)N_NODES * 128 * 2);
    _Float16* Wt = (_Float16*)(ws + o); o = align256(o + (size_t)128 * 128 * 2);
    int* bcur = (int*)(ws + o);         o = align256(o + (size_t)NBUCKETS * 4);
    int* bucketbuf = (int*)(ws + o);    o = align256(o + (size_t)NBUCKETS * BUCKET_CAP * 4);

    prep_wt_kernel<<<16, 256, 0, stream>>>(W, Wt, bcur);
    fused_gemm_bin_kernel<<<FUSED_NB, 256, 0, stream>>>(h, norm, Wt, t,
                                                        src, dst, bcur, bucketbuf);
    scatter_aggregate_kernel<<<NBUCKETS * 2, 256, 0, stream>>>(bucketbuf, bcur,
                                                               t, norm, b, out);
}

// Round 16
// 59.872 us; speedup vs baseline: 1.1580x; 1.0570x over previous
//
#include <hip/hip_runtime.h>

#define N_NODES 50000
#define N_EDGES 800000

#define NBUCKETS 782      // ceil(50000/64): bucket = dst >> 6 (64 nodes each)
#define BIN_EDGES 4096    // r14 lesson: keep bin blocks small & interleaved
#define BIN_NB 196        // ceil(800000/4096)
#define BUCKET_CAP 1280   // slots per bucket (mean ~1023, sd ~32 -> +8 sigma)

#define GEMM_NB ((N_NODES + 63) / 64)          // 782 gemm tiles (64 rows each)
#define FUSED_NB 980                           // 196*5; bid%5==4 -> bin role

typedef __attribute__((ext_vector_type(4))) _Float16 half4;
typedef __attribute__((ext_vector_type(8))) _Float16 half8;
typedef __attribute__((ext_vector_type(4))) float f32x4;

// -------- Prep: Wt[c][k] = fp16(W[k][c]); block 0 zeroes bcur -------------
// 32 KB fp16 transposed W; L2-hot source for the GEMM role's LDS stage.
__global__ __launch_bounds__(256) void prep_wt_kernel(
    const float* __restrict__ W, _Float16* __restrict__ Wt,
    int* __restrict__ bcur)
{
    const int tid = threadIdx.x;
    if (blockIdx.x == 0) {
        for (int i = tid; i < NBUCKETS; i += 256) bcur[i] = 0;
    }
    const int e = blockIdx.x * 256 + tid;           // 4096 threads
    const int c = e & 127;
    const int k4 = (e >> 7) << 2;
    half4 v;
    v.x = (_Float16)W[(k4 + 0) * 128 + c];
    v.y = (_Float16)W[(k4 + 1) * 128 + c];
    v.z = (_Float16)W[(k4 + 2) * 128 + c];
    v.w = (_Float16)W[(k4 + 3) * 128 + c];
    *(half4*)(Wt + (size_t)c * 128 + k4) = v;
}

// -------- Fused Kernel A: MFMA gemm tiles + edge binning ------------------
// ROUND-12 CONFIG (best measured: 60.1us total): blocks with bid%5==4 bin
// 4096 edges into per-bucket streams of PACKED ints (src | (dst&63)<<16;
// src<65536). Other blocks: one 64-row GEMM tile (4 waves x 16 rows),
// mfma_f32_16x16x32_f16; Wt staged once into LDS (pad 136 halves ->
// conflict-free ds_read_b128), A-frags straight from h. hist (3.1 KB)
// unioned with WtS (34.8 KB) — the two roles never share.
// Fragment layout (guide-verified 16x16x32): A/B lane l&15 = row/col,
// k = (l>>4)*8 + j; C/D col = l&15, row = (l>>4)*4 + reg.
// SESSION RULE (rounds 2 & 4): no min-waves clause — it collapses VGPRs and
// spills the accumulators (WRITE_SIZE tripwire 12.5 MB -> 183-564 MB).
__global__ __launch_bounds__(256) void fused_gemm_bin_kernel(
    const float* __restrict__ h, const float* __restrict__ norm,
    const _Float16* __restrict__ Wt, _Float16* __restrict__ t,
    const int* __restrict__ src, const int* __restrict__ dst,
    int* __restrict__ bcur, int* __restrict__ bucketbuf)
{
    __shared__ __align__(16) char smem[128 * 136 * 2];  // 34.8 KB union
    _Float16* WtS = (_Float16*)smem;                    // gemm role
    int* hist = (int*)smem;                             // bin role (3.1 KB)
    const int tid = threadIdx.x;
    const int bid = blockIdx.x;

    if (bid % 5 == 4) {
        // ---- bin role: 4096 edges -> 782 bucket streams --------------------
        const int bs = (bid / 5) * BIN_EDGES;
        for (int i = tid; i < NBUCKETS; i += 256) hist[i] = 0;
        __syncthreads();
#pragma unroll
        for (int j = 0; j < 4; ++j) {
            int e4 = bs + (j * 256 + tid) * 4;
            if (e4 < N_EDGES) {               // 4096 & 1280 both %4==0
                int4 d4 = *(const int4*)(dst + e4);
                atomicAdd(&hist[d4.x >> 6], 1);
                atomicAdd(&hist[d4.y >> 6], 1);
                atomicAdd(&hist[d4.z >> 6], 1);
                atomicAdd(&hist[d4.w >> 6], 1);
            }
        }
        __syncthreads();
        for (int i = tid; i < NBUCKETS; i += 256) {
            int hc = hist[i];
            hist[i] = hc ? atomicAdd(&bcur[i], hc) : 0;
        }
        __syncthreads();
#pragma unroll
        for (int j = 0; j < 4; ++j) {
            int e4 = bs + (j * 256 + tid) * 4;
            if (e4 < N_EDGES) {
                int4 d4 = *(const int4*)(dst + e4);
                int4 s4 = *(const int4*)(src + e4);
                int b0, p;
                b0 = d4.x >> 6; p = atomicAdd(&hist[b0], 1);
                bucketbuf[(size_t)b0 * BUCKET_CAP + p] = s4.x | ((d4.x & 63) << 16);
                b0 = d4.y >> 6; p = atomicAdd(&hist[b0], 1);
                bucketbuf[(size_t)b0 * BUCKET_CAP + p] = s4.y | ((d4.y & 63) << 16);
                b0 = d4.z >> 6; p = atomicAdd(&hist[b0], 1);
                bucketbuf[(size_t)b0 * BUCKET_CAP + p] = s4.z | ((d4.z & 63) << 16);
                b0 = d4.w >> 6; p = atomicAdd(&hist[b0], 1);
                bucketbuf[(size_t)b0 * BUCKET_CAP + p] = s4.w | ((d4.w & 63) << 16);
            }
        }
        return;
    }

    // ---- gemm role: one 64-row tile, 4 waves x 16 rows ---------------------
    const int gemm_id = bid - bid / 5;
    if (gemm_id >= GEMM_NB) return;
    const int rbase = gemm_id * 64;

    // stage Wt into LDS once (8 x half8 per thread, coalesced), one barrier
#pragma unroll
    for (int i = 0; i < 8; ++i) {
        int f = i * 256 + tid;            // 0..2047
        int c = f >> 4;                   // 0..127
        int k8 = (f & 15) << 3;           // 0..120
        *(half8*)(WtS + c * 136 + k8) = *(const half8*)(Wt + (size_t)c * 128 + k8);
    }
    __syncthreads();

    const int wid = tid >> 6, lane = tid & 63;
    const int lrow = lane & 15;            // A row / B col within 16-tile
    const int khi = (lane >> 4) << 3;      // k octet (in halves)
    const int r0 = wid * 16;
    const int gr = rbase + r0 + lrow;      // this lane's A row

    // A fragments straight from h (fp32 -> fp16), 8 float4 loads in flight
    half8 a[4];
#pragma unroll
    for (int ks = 0; ks < 4; ++ks) {
        float4 f0 = make_float4(0.f, 0.f, 0.f, 0.f);
        float4 f1 = f0;
        if (gr < N_NODES) {
            const float* hp = h + (size_t)gr * 128 + ks * 32 + khi;
            f0 = *(const float4*)hp;
            f1 = *(const float4*)(hp + 4);
        }
        half8 av;
        av[0] = (_Float16)f0.x; av[1] = (_Float16)f0.y;
        av[2] = (_Float16)f0.z; av[3] = (_Float16)f0.w;
        av[4] = (_Float16)f1.x; av[5] = (_Float16)f1.y;
        av[6] = (_Float16)f1.z; av[7] = (_Float16)f1.w;
        a[ks] = av;
    }

    // per-lane output rows (fixed across col-tiles) + their norms (L2-hot)
    const int rq = rbase + r0 + ((lane >> 4) << 2);
    float nv[4];
#pragma unroll
    for (int reg = 0; reg < 4; ++reg)
        nv[reg] = (rq + reg < N_NODES) ? norm[rq + reg] : 0.f;

#pragma unroll
    for (int ct = 0; ct < 8; ++ct) {
        const int c0 = ct * 16;
        f32x4 acc = {0.f, 0.f, 0.f, 0.f};
#pragma unroll
        for (int ks = 0; ks < 4; ++ks) {
            half8 bf = *(const half8*)(WtS + (c0 + lrow) * 136 + ks * 32 + khi);
            acc = __builtin_amdgcn_mfma_f32_16x16x32_f16(a[ks], bf, acc, 0, 0, 0);
        }
#pragma unroll
        for (int reg = 0; reg < 4; ++reg) {
            if (rq + reg < N_NODES)
                t[(size_t)(rq + reg) * 128 + c0 + lrow] = (_Float16)(acc[reg] * nv[reg]);
        }
    }
}

// -------- Fused scatter+aggregate: sort bucket in LDS, gather, finalize ---
// One block per 64-node bucket (782 blocks — the r12 config; r13/r15
// splits both regressed). ROUND-16 CHANGE: the bucket's packed ints are
// staged into LDS (int4-vectorized) during the histogram pass, so the
// placement pass is LDS->LDS — bucketbuf is read from global ONCE, not
// twice (saves ~3.2 MB global traffic + one full-latency pass per block).
// Phase 3: 16 groups of 16 lanes aggregate 4 nodes each (x4-unrolled
// gathers); deg-0 nodes produce acc=0 -> out = b.
__global__ __launch_bounds__(256) void scatter_aggregate_kernel(
    const int* __restrict__ bucketbuf, const int* __restrict__ bcur,
    const _Float16* __restrict__ t, const float* __restrict__ norm,
    const float* __restrict__ bias, float* __restrict__ out)
{
    const int tid = threadIdx.x;
    const int b = blockIdx.x;
    __shared__ int cnt[64];     // per-node counts (kept)
    __shared__ int endp[64];    // inclusive scan (segment ends)
    __shared__ int lcur[64];    // running cursors (start -> end)
    __shared__ int raw[BUCKET_CAP];     // staged packed ints (5 KB)
    __shared__ int slist[BUCKET_CAP];   // sorted srcs (5 KB)

    if (tid < 64) cnt[tid] = 0;
    __syncthreads();

    const int n = bcur[b];
    const int* buf = bucketbuf + (size_t)b * BUCKET_CAP;
    // single global pass: int4 load -> LDS stage + histogram.
    // (i4 < n and i4%4==0 imply i4+3 < BUCKET_CAP since BUCKET_CAP%4==0,
    //  so the full int4 is in-bounds; only elements < n are histogrammed.)
    for (int i4 = tid * 4; i4 < n; i4 += 1024) {
        int4 v = *(const int4*)(buf + i4);
        *(int4*)(raw + i4) = v;
        atomicAdd(&cnt[(v.x >> 16) & 63], 1);
        if (i4 + 1 < n) atomicAdd(&cnt[(v.y >> 16) & 63], 1);
        if (i4 + 2 < n) atomicAdd(&cnt[(v.z >> 16) & 63], 1);
        if (i4 + 3 < n) atomicAdd(&cnt[(v.w >> 16) & 63], 1);
    }
    __syncthreads();

    if (tid < 64) {             // single-wave inclusive scan over 64 counts
        int c = cnt[tid];
        int inc = c;
#pragma unroll
        for (int d = 1; d < 64; d <<= 1) {
            int u = __shfl_up(inc, d);
            if (tid >= d) inc += u;
        }
        endp[tid] = inc;
        lcur[tid] = inc - c;    // exclusive start
    }
    __syncthreads();

    // placement pass: LDS -> LDS
    for (int i = tid; i < n; i += 256) {
        int p = raw[i];
        int pos = atomicAdd(&lcur[(p >> 16) & 63], 1);
        slist[pos] = p & 0xFFFF;
    }
    __syncthreads();

    // ---- aggregate phase: group q handles nodes q, q+16, q+32, q+48 -------
    const int q = tid >> 4, l = tid & 15, c = l << 3;
    const float4 b0 = *(const float4*)(bias + c);
    const float4 b1 = *(const float4*)(bias + c + 4);

    for (int r = 0; r < 4; ++r) {
        const int nl = q + (r << 4);
        const int g = b * 64 + nl;
        if (g >= N_NODES) continue;
        const int i1 = endp[nl];
        const int i0 = i1 - cnt[nl];

        float acc0[8], acc1[8], acc2[8], acc3[8];
#pragma unroll
        for (int j = 0; j < 8; ++j) {
            acc0[j] = 0.f; acc1[j] = 0.f; acc2[j] = 0.f; acc3[j] = 0.f;
        }

        int i = i0;
        for (; i + 4 <= i1; i += 4) {
            int s0 = slist[i], s1 = slist[i + 1];
            int s2 = slist[i + 2], s3 = slist[i + 3];
            half8 v0 = *(const half8*)(t + (size_t)s0 * 128 + c);
            half8 v1 = *(const half8*)(t + (size_t)s1 * 128 + c);
            half8 v2 = *(const half8*)(t + (size_t)s2 * 128 + c);
            half8 v3 = *(const half8*)(t + (size_t)s3 * 128 + c);
#pragma unroll
            for (int j = 0; j < 8; ++j) {
                acc0[j] += (float)v0[j]; acc1[j] += (float)v1[j];
                acc2[j] += (float)v2[j]; acc3[j] += (float)v3[j];
            }
        }
        for (; i < i1; ++i) {
            int s0 = slist[i];
            half8 v0 = *(const half8*)(t + (size_t)s0 * 128 + c);
#pragma unroll
            for (int j = 0; j < 8; ++j) acc0[j] += (float)v0[j];
        }

        const float nv = norm[g];
        float4 o0 = make_float4((acc0[0] + acc1[0] + acc2[0] + acc3[0]) * nv + b0.x,
                                (acc0[1] + acc1[1] + acc2[1] + acc3[1]) * nv + b0.y,
                                (acc0[2] + acc1[2] + acc2[2] + acc3[2]) * nv + b0.z,
                                (acc0[3] + acc1[3] + acc2[3] + acc3[3]) * nv + b0.w);
        float4 o1 = make_float4((acc0[4] + acc1[4] + acc2[4] + acc3[4]) * nv + b1.x,
                                (acc0[5] + acc1[5] + acc2[5] + acc3[5]) * nv + b1.y,
                                (acc0[6] + acc1[6] + acc2[6] + acc3[6]) * nv + b1.z,
                                (acc0[7] + acc1[7] + acc2[7] + acc3[7]) * nv + b1.w);
        *(float4*)(out + (size_t)g * 128 + c) = o0;
        *(float4*)(out + (size_t)g * 128 + c + 4) = o1;
    }
}

static inline size_t align256(size_t x) { return (x + 255) & ~(size_t)255; }

extern "C" void kernel_launch(void* const* d_in, const int* in_sizes, int n_in,
                              void* d_out, int out_size, void* d_ws, size_t ws_size,
                              hipStream_t stream)
{
    const float* h    = (const float*)d_in[0];
    const float* norm = (const float*)d_in[1];
    const float* W    = (const float*)d_in[2];
    const float* b    = (const float*)d_in[3];
    const int*   src  = (const int*)d_in[4];
    const int*   dst  = (const int*)d_in[5];
    float* out = (float*)d_out;

    // workspace layout
    char* ws = (char*)d_ws;
    size_t o = 0;
    _Float16* t = (_Float16*)(ws + o);  o = align256(o + (size_t)N_NODES * 128 * 2);
    _Float16* Wt = (_Float16*)(ws + o); o = align256(o + (size_t)128 * 128 * 2);
    int* bcur = (int*)(ws + o);         o = align256(o + (size_t)NBUCKETS * 4);
    int* bucketbuf = (int*)(ws + o);    o = align256(o + (size_t)NBUCKETS * BUCKET_CAP * 4);

    prep_wt_kernel<<<16, 256, 0, stream>>>(W, Wt, bcur);
    fused_gemm_bin_kernel<<<FUSED_NB, 256, 0, stream>>>(h, norm, Wt, t,
                                                        src, dst, bcur, bucketbuf);
    scatter_aggregate_kernel<<<NBUCKETS, 256, 0, stream>>>(bucketbuf, bcur,
                                                           t, norm, b, out);
}